// Round 1
// baseline (419.996 us; speedup 1.0000x reference)
//
#include <hip/hip_runtime.h>
#include <hip/hip_bf16.h>

#define N_ 32
#define C_ 128
#define H_ 56
#define W_ 56
#define K_ 256
#define HW_ (H_*W_)

typedef __attribute__((ext_vector_type(8))) __bf16 bf16x8;
typedef __attribute__((ext_vector_type(8))) unsigned short ushort8;
typedef __attribute__((ext_vector_type(4))) float f32x4;

__device__ __forceinline__ unsigned short f2bf(float f) {
    unsigned int u = __builtin_bit_cast(unsigned int, f);
    u += 0x7FFFu + ((u >> 16) & 1u);   // round-to-nearest-even
    return (unsigned short)(u >> 16);
}

// Repack weights OIHW fp32 -> [tap][k_out][c] bf16 (contiguous c for A staging)
__global__ void repack_w_kernel(const float* __restrict__ w,
                                unsigned short* __restrict__ wp) {
    int idx = blockIdx.x * 256 + threadIdx.x;          // (tap*256 + k)*128 + c
    if (idx >= 9 * K_ * C_) return;
    int c   = idx & (C_ - 1);
    int k   = (idx >> 7) & (K_ - 1);
    int tap = idx >> 15;
    wp[idx] = f2bf(w[(k * C_ + c) * 9 + tap]);
}

// Implicit-GEMM conv: block = 256 k_out x 112 pixels (2 rows of one image).
// K-loop: 9 taps x 4 chunks of 32 channels. 4 waves, wave tile 64x112.
__launch_bounds__(256, 2)
__global__ void conv_mfma_kernel(const float* __restrict__ x,
                                 const unsigned short* __restrict__ wp,
                                 const float* __restrict__ bias,
                                 float* __restrict__ out) {
    // row stride 40 (80B = 20 banks, spreads b128 reads; 16B-aligned rows)
    __shared__ unsigned short Abuf[256 * 40];   // [k_out][kk]
    __shared__ unsigned short Bbuf[112 * 40];   // [pixel][kk]

    const int t    = threadIdx.x;
    const int lane = t & 63;
    const int wid  = t >> 6;
    const int blk  = blockIdx.x;
    const int n    = blk / 28;
    const int rp   = blk % 28;
    const int h0   = rp * 2;

    f32x4 acc[4][7];
    #pragma unroll
    for (int mi = 0; mi < 4; ++mi)
        #pragma unroll
        for (int ni = 0; ni < 7; ++ni)
            acc[mi][ni] = (f32x4){0.f, 0.f, 0.f, 0.f};

    for (int kt = 0; kt < 36; ++kt) {
        const int tap = kt >> 2;
        const int c0  = (kt & 3) * 32;
        const int r   = tap / 3;
        const int s   = tap - 3 * r;

        // ---- stage A: 256 rows x 32 ch, one row per thread, 4x16B ----
        {
            const ushort8* src = (const ushort8*)(wp + ((tap * K_ + t) * C_ + c0));
            ushort8 v0 = src[0], v1 = src[1], v2 = src[2], v3 = src[3];
            ushort8* dst = (ushort8*)(&Abuf[t * 40]);
            dst[0] = v0; dst[1] = v1; dst[2] = v2; dst[3] = v3;
        }

        // ---- stage B: im2col 112 pixels x 32 ch, zero-padded halo ----
        #pragma unroll
        for (int i = 0; i < 14; ++i) {
            int e  = i * 256 + t;        // e = kk*112 + p
            int kk = e / 112;
            int p  = e - kk * 112;
            int hr = (p >= 56) ? 1 : 0;
            int pw = p - hr * 56;
            int hin = h0 + hr + r - 1;
            int win = pw + s - 1;
            float v = 0.f;
            if ((unsigned)hin < 56u && (unsigned)win < 56u)
                v = x[((n * C_ + c0 + kk) * H_ + hin) * W_ + win];
            Bbuf[p * 40 + kk] = f2bf(v);
        }

        __syncthreads();

        // ---- MFMA: wave tile 64x112 = 4 M-frags x 7 N-frags ----
        const unsigned short* Ab = &Abuf[(wid * 64 + (lane & 15)) * 40 + (lane >> 4) * 8];
        const unsigned short* Bb = &Bbuf[(lane & 15) * 40 + (lane >> 4) * 8];

        bf16x8 bfr[7];
        #pragma unroll
        for (int ni = 0; ni < 7; ++ni)
            bfr[ni] = __builtin_bit_cast(bf16x8, *(const ushort8*)(Bb + ni * 640));

        #pragma unroll
        for (int mi = 0; mi < 4; ++mi) {
            bf16x8 a = __builtin_bit_cast(bf16x8, *(const ushort8*)(Ab + mi * 640));
            #pragma unroll
            for (int ni = 0; ni < 7; ++ni)
                acc[mi][ni] = __builtin_amdgcn_mfma_f32_16x16x32_bf16(
                    a, bfr[ni], acc[mi][ni], 0, 0, 0);
        }

        __syncthreads();
    }

    // ---- epilogue: bias + store fp32 ----
    const int colp  = lane & 15;
    const int rbase = (lane >> 4) * 4;
    #pragma unroll
    for (int mi = 0; mi < 4; ++mi) {
        #pragma unroll
        for (int j = 0; j < 4; ++j) {
            int kout = wid * 64 + mi * 16 + rbase + j;
            float bv = bias[kout];
            #pragma unroll
            for (int ni = 0; ni < 7; ++ni) {
                int p  = ni * 16 + colp;
                int hr = (p >= 56) ? 1 : 0;
                int pw = p - hr * 56;
                out[((n * K_ + kout) * H_ + h0 + hr) * W_ + pw] = acc[mi][ni][j] + bv;
            }
        }
    }
}

// Safety fallback if workspace is too small for the weight repack.
__global__ void conv_naive_kernel(const float* __restrict__ x,
                                  const float* __restrict__ w,
                                  const float* __restrict__ b,
                                  float* __restrict__ out) {
    int idx = blockIdx.x * 256 + threadIdx.x;
    if (idx >= N_ * K_ * HW_) return;
    int pw = idx % 56; int tmp = idx / 56;
    int h  = tmp % 56; tmp /= 56;
    int k  = tmp % 256; int n = tmp / 256;
    float acc = b[k];
    for (int c = 0; c < C_; ++c)
        for (int r = 0; r < 3; ++r) {
            int hin = h + r - 1;
            if ((unsigned)hin >= 56u) continue;
            for (int s = 0; s < 3; ++s) {
                int win = pw + s - 1;
                if ((unsigned)win >= 56u) continue;
                acc += x[((n * C_ + c) * H_ + hin) * W_ + win] * w[(k * C_ + c) * 9 + r * 3 + s];
            }
        }
    out[idx] = acc;
}

extern "C" void kernel_launch(void* const* d_in, const int* in_sizes, int n_in,
                              void* d_out, int out_size, void* d_ws, size_t ws_size,
                              hipStream_t stream) {
    const float* x = (const float*)d_in[0];
    const float* w = (const float*)d_in[1];
    const float* b = (const float*)d_in[2];
    float* out = (float*)d_out;

    const size_t wp_bytes = (size_t)9 * K_ * C_ * sizeof(unsigned short);
    if (ws_size >= wp_bytes) {
        unsigned short* wp = (unsigned short*)d_ws;
        repack_w_kernel<<<(9 * K_ * C_ + 255) / 256, 256, 0, stream>>>(w, wp);
        conv_mfma_kernel<<<32 * 28, 256, 0, stream>>>(x, wp, b, out);
    } else {
        conv_naive_kernel<<<(N_ * K_ * HW_ + 255) / 256, 256, 0, stream>>>(x, w, b, out);
    }
}

// Round 3
// 85.241 us; speedup vs baseline: 4.9272x; 4.9272x over previous
//
#include <hip/hip_runtime.h>
#include <hip/hip_bf16.h>

#define N_ 32
#define C_ 128
#define H_ 56
#define W_ 56
#define K_ 256
#define HW_ (H_*W_)

typedef __attribute__((ext_vector_type(8))) __bf16 bf16x8;
typedef __attribute__((ext_vector_type(8))) unsigned short ushort8;
typedef __attribute__((ext_vector_type(4))) float f32x4;

__device__ __forceinline__ unsigned short f2bf(float f) {
    unsigned int u = __builtin_bit_cast(unsigned int, f);
    u += 0x7FFFu + ((u >> 16) & 1u);   // round-to-nearest-even
    return (unsigned short)(u >> 16);
}

// Repack weights OIHW fp32 -> MFMA-fragment-major bf16:
// wp2[((tap*16 + kg)*4 + cc)*64 + lane][j]  (ushort8 units)
//   k = kg*16 + (lane&15), c = cc*32 + (lane>>4)*8 + j
// => each A fragment load is global_load_dwordx4 at base + lane*16B (coalesced 1KB)
__global__ void repack_w2_kernel(const float* __restrict__ w,
                                 unsigned short* __restrict__ wp2) {
    int o = blockIdx.x * 256 + threadIdx.x;
    if (o >= 9 * 16 * 4 * 64 * 8) return;
    int j   = o & 7;
    int l   = (o >> 3) & 63;
    int cc  = (o >> 9) & 3;
    int kg  = (o >> 11) & 15;
    int tap = o >> 15;
    int k = kg * 16 + (l & 15);
    int c = cc * 32 + (l >> 4) * 8 + j;
    wp2[o] = f2bf(w[(k * C_ + c) * 9 + tap]);
}

// Implicit-GEMM conv, tap-loop-inside-tile structure.
// Block: 128 kout x 112 pixels (2 output rows of one image). 4 waves,
// wave tile 32x112 (mi=2, ni=7). Outer loop: 4 chunks of 32 channels.
// Per chunk: stage Xt[4][58][32ch] (halo zero-filled, row stride 40) once,
// then 9 taps x 14 MFMA reading B at compile-time LDS offsets, A direct
// from L2-resident repacked weights. 2 barriers per chunk (8 total).
__launch_bounds__(256, 2)
__global__ void conv_mfma2_kernel(const float* __restrict__ x,
                                  const unsigned short* __restrict__ wp2,
                                  const float* __restrict__ bias,
                                  float* __restrict__ out) {
    __shared__ unsigned short Xt[4 * 58 * 40];   // 18560 B

    const int t    = threadIdx.x;
    const int lane = t & 63;
    const int wid  = t >> 6;

    // bijective XCD swizzle (1792 % 8 == 0): contiguous 224-chunks per XCD
    const int b    = blockIdx.x;
    const int orig = (b & 7) * 224 + (b >> 3);
    const int kb   = orig & 1;          // which 128-kout half
    const int cell = orig >> 1;
    const int n    = cell / 28;
    const int rp   = cell - n * 28;
    const int h0   = rp * 2;

    const int lp = lane & 15;           // pixel sub-index
    const int lk = lane >> 4;           // k-subgroup

    // per-ni B base pointers (tap-independent); tap adds (r*58+s)*40 halfs
    const unsigned short* bp[7];
    #pragma unroll
    for (int ni = 0; ni < 7; ++ni) {
        int p  = ni * 16 + lp;
        int hr = (p >= 56) ? 1 : 0;
        int pw = p - hr * 56;
        bp[ni] = &Xt[(hr * 58 + pw) * 40 + lk * 8];
    }

    const int kgbase = kb * 8 + wid * 2;

    f32x4 acc[2][7];
    #pragma unroll
    for (int mi = 0; mi < 2; ++mi)
        #pragma unroll
        for (int ni = 0; ni < 7; ++ni)
            acc[mi][ni] = (f32x4){0.f, 0.f, 0.f, 0.f};

    for (int cc = 0; cc < 4; ++cc) {
        if (cc) __syncthreads();

        // ---- stage Xt: 232 (hh,ww) columns x 4 csub, one b128 write each ----
        #pragma unroll
        for (int i = 0; i < 4; ++i) {
            int it = i * 256 + t;
            if (it < 928) {
                int csub = (it >= 232) + (it >= 464) + (it >= 696);
                int col  = it - 232 * csub;
                int hh   = col / 58;
                int ww   = col - 58 * hh;
                int hin  = h0 + hh - 1;
                int win  = ww - 1;
                ushort8 v = {0, 0, 0, 0, 0, 0, 0, 0};
                if ((unsigned)hin < 56u && (unsigned)win < 56u) {
                    const float* xp = x + (((n * C_ + cc * 32 + csub * 8) * H_ + hin) * W_ + win);
                    #pragma unroll
                    for (int k2 = 0; k2 < 8; ++k2)
                        v[k2] = f2bf(xp[k2 * HW_]);
                }
                *(ushort8*)(&Xt[col * 40 + csub * 8]) = v;
            }
        }
        __syncthreads();

        // ---- 9 taps x (2 A-frags from L2 + 7 B-frags from LDS + 14 MFMA) ----
        const int fb8 = (kgbase * 4 + cc) * 64 + lane;   // ushort8 index, mi=0
        #pragma unroll
        for (int tap = 0; tap < 9; ++tap) {
            const int r    = tap / 3;
            const int s    = tap - 3 * r;
            const int toff = (r * 58 + s) * 40;          // compile-time per tap

            bf16x8 a0 = __builtin_bit_cast(bf16x8, ((const ushort8*)wp2)[tap * 4096 + fb8]);
            bf16x8 a1 = __builtin_bit_cast(bf16x8, ((const ushort8*)wp2)[tap * 4096 + fb8 + 256]);

            bf16x8 bfr[7];
            #pragma unroll
            for (int ni = 0; ni < 7; ++ni)
                bfr[ni] = __builtin_bit_cast(bf16x8, *(const ushort8*)(bp[ni] + toff));

            #pragma unroll
            for (int ni = 0; ni < 7; ++ni)
                acc[0][ni] = __builtin_amdgcn_mfma_f32_16x16x32_bf16(a0, bfr[ni], acc[0][ni], 0, 0, 0);
            #pragma unroll
            for (int ni = 0; ni < 7; ++ni)
                acc[1][ni] = __builtin_amdgcn_mfma_f32_16x16x32_bf16(a1, bfr[ni], acc[1][ni], 0, 0, 0);
        }
    }

    // ---- epilogue: bias + fp32 store ----
    #pragma unroll
    for (int mi = 0; mi < 2; ++mi) {
        #pragma unroll
        for (int j = 0; j < 4; ++j) {
            int kout = kb * 128 + wid * 32 + mi * 16 + lk * 4 + j;
            float bv = bias[kout];
            float* op = out + ((n * K_ + kout) * H_ + h0) * W_;
            #pragma unroll
            for (int ni = 0; ni < 7; ++ni) {
                int p  = ni * 16 + lp;
                int hr = (p >= 56) ? 1 : 0;
                int pw = p - hr * 56;
                op[hr * W_ + pw] = acc[mi][ni][j] + bv;
            }
        }
    }
}

// Safety fallback if workspace is too small for the weight repack.
__global__ void conv_naive_kernel(const float* __restrict__ x,
                                  const float* __restrict__ w,
                                  const float* __restrict__ b,
                                  float* __restrict__ out) {
    int idx = blockIdx.x * 256 + threadIdx.x;
    if (idx >= N_ * K_ * HW_) return;
    int pw = idx % 56; int tmp = idx / 56;
    int h  = tmp % 56; tmp /= 56;
    int k  = tmp % 256; int n = tmp / 256;
    float acc = b[k];
    for (int c = 0; c < C_; ++c)
        for (int r = 0; r < 3; ++r) {
            int hin = h + r - 1;
            if ((unsigned)hin >= 56u) continue;
            for (int s = 0; s < 3; ++s) {
                int win = pw + s - 1;
                if ((unsigned)win >= 56u) continue;
                acc += x[((n * C_ + c) * H_ + hin) * W_ + win] * w[(k * C_ + c) * 9 + r * 3 + s];
            }
        }
    out[idx] = acc;
}

extern "C" void kernel_launch(void* const* d_in, const int* in_sizes, int n_in,
                              void* d_out, int out_size, void* d_ws, size_t ws_size,
                              hipStream_t stream) {
    const float* x = (const float*)d_in[0];
    const float* w = (const float*)d_in[1];
    const float* b = (const float*)d_in[2];
    float* out = (float*)d_out;

    const size_t wp_bytes = (size_t)9 * 16 * 4 * 64 * 8 * sizeof(unsigned short); // 576 KB
    if (ws_size >= wp_bytes) {
        unsigned short* wp2 = (unsigned short*)d_ws;
        repack_w2_kernel<<<(9 * 16 * 4 * 64 * 8 + 255) / 256, 256, 0, stream>>>(w, wp2);
        conv_mfma2_kernel<<<1792, 256, 0, stream>>>(x, wp2, b, out);
    } else {
        conv_naive_kernel<<<(N_ * K_ * HW_ + 255) / 256, 256, 0, stream>>>(x, w, b, out);
    }
}

// Round 4
// 84.685 us; speedup vs baseline: 4.9595x; 1.0066x over previous
//
#include <hip/hip_runtime.h>
#include <hip/hip_bf16.h>

#define N_ 32
#define C_ 128
#define H_ 56
#define W_ 56
#define K_ 256
#define HW_ (H_*W_)

typedef __attribute__((ext_vector_type(8))) __bf16 bf16x8;
typedef __attribute__((ext_vector_type(8))) unsigned short ushort8;
typedef __attribute__((ext_vector_type(4))) float f32x4;

__device__ __forceinline__ unsigned short f2bf(float f) {
    unsigned int u = __builtin_bit_cast(unsigned int, f);
    u += 0x7FFFu + ((u >> 16) & 1u);   // round-to-nearest-even
    return (unsigned short)(u >> 16);
}

// Repack weights OIHW fp32 -> MFMA-fragment-major bf16:
// wp2[((tap*16 + kg)*4 + cc)*64 + lane][j]  (ushort8 units)
//   k = kg*16 + (lane&15), c = cc*32 + (lane>>4)*8 + j
__global__ void repack_w2_kernel(const float* __restrict__ w,
                                 unsigned short* __restrict__ wp2) {
    int o = blockIdx.x * 256 + threadIdx.x;
    if (o >= 9 * 16 * 4 * 64 * 8) return;
    int j   = o & 7;
    int l   = (o >> 3) & 63;
    int cc  = (o >> 9) & 3;
    int kg  = (o >> 11) & 15;
    int tap = o >> 15;
    int k = kg * 16 + (l & 15);
    int c = cc * 32 + (l >> 4) * 8 + j;
    wp2[o] = f2bf(w[(k * C_ + c) * 9 + tap]);
}

// Implicit-GEMM conv, tap-in-tile + double-buffered Xt + async-stage split.
// Block: 256 kout x 112 px (2 output rows). 4 waves, wave tile 64x112
// (mi=4, ni=7). Outer: 4 chunks of 32 channels; per chunk: 9 taps x 28 MFMA
// per wave, B from LDS (reused 4x per fragment), A direct from L2-resident
// repacked weights. STAGE_LOAD(cc+1) issued before the MFMA phase (latency
// hides under 252 MFMAs), STAGE_WRITE after; one barrier per chunk.
__launch_bounds__(256, 2)
__global__ void conv_mfma3_kernel(const float* __restrict__ x,
                                  const unsigned short* __restrict__ wp2,
                                  const float* __restrict__ bias,
                                  float* __restrict__ out) {
    __shared__ unsigned short Xt[2][232 * 40];   // 2 x 18560 B

    const int t    = threadIdx.x;
    const int lane = t & 63;
    const int wid  = t >> 6;

    // bijective XCD swizzle (896 % 8 == 0): 112 contiguous blocks per XCD
    const int b    = blockIdx.x;
    const int orig = (b & 7) * 112 + (b >> 3);
    const int n    = orig / 28;
    const int rp   = orig - n * 28;
    const int h0   = rp * 2;

    const int lp = lane & 15;           // pixel sub-index
    const int lk = lane >> 4;           // k-subgroup

    // per-ni B offsets within a buffer (tap adds (r*58+s)*40)
    int bofs[7];
    #pragma unroll
    for (int ni = 0; ni < 7; ++ni) {
        int p  = ni * 16 + lp;
        int hr = (p >= 56) ? 1 : 0;
        int pw = p - hr * 56;
        bofs[ni] = (hr * 58 + pw) * 40 + lk * 8;
    }

    // chunk-invariant staging geometry: 928 items = 232 (hh,ww) cols x 4 csub
    bool  ok[4], v928[4];
    const float* xp[4];
    int   ldsw[4];
    #pragma unroll
    for (int i = 0; i < 4; ++i) {
        int it = i * 256 + t;
        v928[i] = (it < 928);
        int itc  = v928[i] ? it : 0;
        int csub = (itc >= 232) + (itc >= 464) + (itc >= 696);
        int col  = itc - 232 * csub;
        int hh   = col / 58;
        int ww   = col - 58 * hh;
        int hin  = h0 + hh - 1;
        int win  = ww - 1;
        ok[i]   = v928[i] && (unsigned)hin < 56u && (unsigned)win < 56u;
        xp[i]   = x + (((n * C_ + csub * 8) * H_ + hin) * W_ + win);
        ldsw[i] = col * 40 + csub * 8;
    }

    float xv[4][8];

    // ---- STAGE_LOAD / STAGE_WRITE as macros over (chunk, buf) ----
#define STAGE_LOAD(CH)                                                 \
    _Pragma("unroll")                                                  \
    for (int i = 0; i < 4; ++i)                                        \
        _Pragma("unroll")                                              \
        for (int j = 0; j < 8; ++j)                                    \
            xv[i][j] = ok[i] ? xp[i][((CH) * 32 + j) * HW_] : 0.f;

#define STAGE_WRITE(BUF)                                               \
    _Pragma("unroll")                                                  \
    for (int i = 0; i < 4; ++i)                                        \
        if (v928[i]) {                                                 \
            ushort8 v;                                                 \
            _Pragma("unroll")                                          \
            for (int j = 0; j < 8; ++j) v[j] = f2bf(xv[i][j]);         \
            *(ushort8*)(&Xt[BUF][ldsw[i]]) = v;                        \
        }

    f32x4 acc[4][7];
    #pragma unroll
    for (int mi = 0; mi < 4; ++mi)
        #pragma unroll
        for (int ni = 0; ni < 7; ++ni)
            acc[mi][ni] = (f32x4){0.f, 0.f, 0.f, 0.f};

    // prologue: stage chunk 0 into buf 0
    STAGE_LOAD(0)
    STAGE_WRITE(0)
    __syncthreads();

    const ushort8* W8 = (const ushort8*)wp2;

    for (int cc = 0; cc < 4; ++cc) {
        const int cur = cc & 1;

        if (cc < 3) { STAGE_LOAD(cc + 1) }   // global loads in flight under MFMAs

        const int tb = wid * 1024 + cc * 64 + lane;
        #pragma unroll
        for (int tap = 0; tap < 9; ++tap) {
            const int r    = tap / 3;
            const int s    = tap - 3 * r;
            const int toff = (r * 58 + s) * 40;          // compile-time per tap

            bf16x8 a[4];
            #pragma unroll
            for (int mi = 0; mi < 4; ++mi)
                a[mi] = __builtin_bit_cast(bf16x8, W8[tap * 4096 + tb + mi * 256]);

            bf16x8 bfr[7];
            #pragma unroll
            for (int ni = 0; ni < 7; ++ni)
                bfr[ni] = __builtin_bit_cast(bf16x8,
                    *(const ushort8*)(&Xt[cur][bofs[ni] + toff]));

            #pragma unroll
            for (int ni = 0; ni < 7; ++ni)
                #pragma unroll
                for (int mi = 0; mi < 4; ++mi)
                    acc[mi][ni] = __builtin_amdgcn_mfma_f32_16x16x32_bf16(
                        a[mi], bfr[ni], acc[mi][ni], 0, 0, 0);
        }

        if (cc < 3) {
            STAGE_WRITE(cur ^ 1)
            __syncthreads();
        }
    }

    // ---- epilogue: bias + fp32 store ----
    #pragma unroll
    for (int mi = 0; mi < 4; ++mi) {
        #pragma unroll
        for (int j = 0; j < 4; ++j) {
            int kout = wid * 64 + mi * 16 + lk * 4 + j;
            float bv = bias[kout];
            float* op = out + ((n * K_ + kout) * H_ + h0) * W_;
            #pragma unroll
            for (int ni = 0; ni < 7; ++ni) {
                int p  = ni * 16 + lp;
                int hr = (p >= 56) ? 1 : 0;
                int pw = p - hr * 56;
                op[hr * W_ + pw] = acc[mi][ni][j] + bv;
            }
        }
    }
#undef STAGE_LOAD
#undef STAGE_WRITE
}

// Safety fallback if workspace is too small for the weight repack.
__global__ void conv_naive_kernel(const float* __restrict__ x,
                                  const float* __restrict__ w,
                                  const float* __restrict__ b,
                                  float* __restrict__ out) {
    int idx = blockIdx.x * 256 + threadIdx.x;
    if (idx >= N_ * K_ * HW_) return;
    int pw = idx % 56; int tmp = idx / 56;
    int h  = tmp % 56; tmp /= 56;
    int k  = tmp % 256; int n = tmp / 256;
    float acc = b[k];
    for (int c = 0; c < C_; ++c)
        for (int r = 0; r < 3; ++r) {
            int hin = h + r - 1;
            if ((unsigned)hin >= 56u) continue;
            for (int s = 0; s < 3; ++s) {
                int win = pw + s - 1;
                if ((unsigned)win >= 56u) continue;
                acc += x[((n * C_ + c) * H_ + hin) * W_ + win] * w[(k * C_ + c) * 9 + r * 3 + s];
            }
        }
    out[idx] = acc;
}

extern "C" void kernel_launch(void* const* d_in, const int* in_sizes, int n_in,
                              void* d_out, int out_size, void* d_ws, size_t ws_size,
                              hipStream_t stream) {
    const float* x = (const float*)d_in[0];
    const float* w = (const float*)d_in[1];
    const float* b = (const float*)d_in[2];
    float* out = (float*)d_out;

    const size_t wp_bytes = (size_t)9 * 16 * 4 * 64 * 8 * sizeof(unsigned short); // 576 KB
    if (ws_size >= wp_bytes) {
        unsigned short* wp2 = (unsigned short*)d_ws;
        repack_w2_kernel<<<(9 * 16 * 4 * 64 * 8 + 255) / 256, 256, 0, stream>>>(w, wp2);
        conv_mfma3_kernel<<<896, 256, 0, stream>>>(x, wp2, b, out);
    } else {
        conv_naive_kernel<<<(N_ * K_ * HW_ + 255) / 256, 256, 0, stream>>>(x, w, b, out);
    }
}